// Round 1
// baseline (500.337 us; speedup 1.0000x reference)
//
#include <hip/hip_runtime.h>
#include <hip/hip_bf16.h>

typedef __hip_bfloat16 bf16;
typedef float v4f __attribute__((ext_vector_type(4)));
typedef short v8s __attribute__((ext_vector_type(8)));

typedef const __attribute__((address_space(1))) void gvoid;
typedef __attribute__((address_space(3))) void lvoid;

__device__ __forceinline__ void async16(const void* g, void* l) {
  __builtin_amdgcn_global_load_lds((gvoid*)g, (lvoid*)l, 16, 0, 0);
}

__device__ __forceinline__ unsigned short f2bf(float v) {
  __hip_bfloat16 h = __float2bfloat16(v);
  return *(unsigned short*)&h;
}
__device__ __forceinline__ float bflo(unsigned dw) {
  unsigned u = dw << 16;
  return *(float*)&u;
}
__device__ __forceinline__ float bfhi(unsigned dw) {
  unsigned u = dw & 0xffff0000u;
  return *(float*)&u;
}

// cardinal cubic B-spline on [0,4], 0 outside. Reference bspline(t) == b3(4t),
// wavelet(t) == b3(8t) - b3(8t-4). Clamp makes u>=4 exactly 0 (64-108+48-4).
__device__ __forceinline__ float b3(float u) {
  u = fminf(fmaxf(u, 0.f), 4.f);
  float t1 = fmaxf(u - 1.f, 0.f);
  float t2 = fmaxf(u - 2.f, 0.f);
  float t3 = fmaxf(u - 3.f, 0.f);
  float c0 = u * u * u;
  float c1 = t1 * t1 * t1;
  float c2 = t2 * t2 * t2;
  float c3 = t3 * t3 * t3;
  return (c0 - 4.f * c1 + 6.f * c2 - 4.f * c3) * (1.f / 6.f);
}

// m97-style NT GEMM mainloop (used by gemm_proj): C[128 x NI*32] tile.
template <int NI, int BK>
__device__ __forceinline__ void mfma_loop(const bf16* __restrict__ A,
                                          const bf16* __restrict__ B, int lda,
                                          int ldb, int kLen, bf16* As, bf16* Bs,
                                          v4f acc[4][NI]) {
  const int tid = threadIdx.x;
  const int wave = tid >> 6;
  const int lane = tid & 63;
  const int quad = lane >> 4;
  const int r16 = lane & 15;
  const int wm = (wave >> 1) * 64;
  const int wn = (wave & 1) * (NI * 16);
  constexpr int CPR = BK / 8;          // 16B chunks per row
  constexpr int AQ = 128 * CPR / 256;  // async groups for A
  constexpr int BQ = NI * 32 * CPR / 256;
  char* AsC = (char*)As;
  char* BsC = (char*)Bs;
  for (int kk = 0; kk < kLen; kk += BK) {
#pragma unroll
    for (int q = 0; q < AQ; ++q) {
      const int ch = tid + 256 * q;
      const int r = ch / CPR, c = (ch % CPR) * 8;
      async16(A + (size_t)r * lda + kk + c, AsC + q * 4096 + wave * 1024);
    }
#pragma unroll
    for (int q = 0; q < BQ; ++q) {
      const int ch = tid + 256 * q;
      const int r = ch / CPR, c = (ch % CPR) * 8;
      async16(B + (size_t)r * ldb + kk + c, BsC + q * 4096 + wave * 1024);
    }
    __syncthreads();
#pragma unroll
    for (int ks = 0; ks < BK / 32; ++ks) {
      v8s af[4], bfr[NI];
#pragma unroll
      for (int mi = 0; mi < 4; ++mi)
        af[mi] =
            *(const v8s*)(As + (wm + mi * 16 + r16) * BK + ks * 32 + quad * 8);
#pragma unroll
      for (int ni = 0; ni < NI; ++ni)
        bfr[ni] =
            *(const v8s*)(Bs + (wn + ni * 16 + r16) * BK + ks * 32 + quad * 8);
#pragma unroll
      for (int mi = 0; mi < 4; ++mi)
#pragma unroll
        for (int ni = 0; ni < NI; ++ni)
          acc[mi][ni] = __builtin_amdgcn_mfma_f32_16x16x32_bf16(
              af[mi], bfr[ni], acc[mi][ni], 0, 0, 0);
    }
    __syncthreads();
  }
}

// per-row: sq-norm + bf16 cast of x into U[:, 0:256]
__global__ void prep(const float* __restrict__ x, bf16* __restrict__ U,
                     float* __restrict__ sq) {
  const int n = blockIdx.x, b = blockIdx.y, t = threadIdx.x;
  const size_t row = (size_t)b * 4096 + n;
  float v = x[row * 256 + t];
  U[row * 1280 + t] = __float2bfloat16(v);
  float s = v * v;
#pragma unroll
  for (int o = 32; o > 0; o >>= 1) s += __shfl_down(s, o, 64);
  __shared__ float ls[4];
  if ((t & 63) == 0) ls[t >> 6] = s;
  __syncthreads();
  if (t == 0) sq[row] = ls[0] + ls[1] + ls[2] + ls[3];
}

// fp32 [z][4096][256] -> bf16 [z][256][4096] (tiled transpose via LDS)
__global__ void transk(const float* __restrict__ src, bf16* __restrict__ dst) {
  __shared__ float tile[64][65];
  const int z = blockIdx.z;
  const float* s = src + (size_t)z * 4096 * 256;
  bf16* d = dst + (size_t)z * 256 * 4096;
  const int n0 = blockIdx.x * 64, d0 = blockIdx.y * 64;
  const int tx = threadIdx.x & 31, ty = threadIdx.x >> 5;
#pragma unroll
  for (int i = 0; i < 8; ++i) {
    const int r = ty + i * 8;
    const float2 v = *(const float2*)(s + (size_t)(n0 + r) * 256 + d0 + tx * 2);
    tile[r][tx * 2] = v.x;
    tile[r][tx * 2 + 1] = v.y;
  }
  __syncthreads();
#pragma unroll
  for (int i = 0; i < 8; ++i) {
    const int c = ty + i * 8;
    __hip_bfloat162 p;
    p.x = __float2bfloat16(tile[tx * 2][c]);
    p.y = __float2bfloat16(tile[tx * 2 + 1][c]);
    *(__hip_bfloat162*)(d + (size_t)(d0 + c) * 4096 + n0 + tx * 2) = p;
  }
}

// WbigT bf16 [128][1280]
__global__ void wbig(const float* __restrict__ Wk, const float* __restrict__ Wl,
                     bf16* __restrict__ WbT) {
  int idx = blockIdx.x * 256 + threadIdx.x;
  if (idx >= 128 * 1280) return;
  int j = idx / 1280, k = idx % 1280;
  int o = j & 63;
  float v = 0.f;
  if (k < 256)
    v = Wk[k * 64 + o] + Wl[k * 128 + j];
  else if (k < 512)
    v = (j < 64) ? Wk[16384 + (k - 256) * 64 + o] : 0.f;
  else if (k < 768)
    v = (j < 64) ? Wk[32768 + (k - 512) * 64 + o] : 0.f;
  else if (k < 1024)
    v = (j >= 64) ? Wk[16384 + (k - 768) * 64 + o] : 0.f;
  else
    v = (j >= 64) ? Wk[32768 + (k - 1024) * 64 + o] : 0.f;
  WbT[idx] = __float2bfloat16(v);
}

// Fused flash-style pass: h_partial[i, d] = sum_j spline(x_i . x_j) * V^T[d, j]
// for BOTH spline kernels (b & w share one S computation + one LUT lookup).
// Per block: i-tile 64 rows, K-split of 1024 j's, one batch, both kernels.
// j-loop: S-tile [64][128] = Xi @ Xj^T (K=256, bf16 MFMA) -> d2/LUT epilogue
// -> P_b,P_w bf16 [64][128] in LDS -> PV: P @ Vt-tile (K=128) accumulate.
// Replaces gemm_s (134 MB kmat write) + 2x gemm_h (2x268 MB kmat read):
// kmat never exists. Numerics identical: same MFMA shapes, same bf16
// rounding points (P bf16, V bf16, partials bf16), same 2048-entry LUT.
// 8 waves (512 thr): S wave-tile 32x32 (2x4 grid), PV wave-tile 32x64.
// LDS: Xi 32K + Xj 32K + Pb 16K + Pw 16K + Vt 32K + lut 8K = 136 KB.
__global__ __launch_bounds__(512, 2) void fused_kh(
    const bf16* __restrict__ U, const float* __restrict__ sqv,
    const bf16* __restrict__ VbB, const bf16* __restrict__ VwB, int bmul,
    bf16* __restrict__ hpart) {
  __shared__ __align__(16) bf16 Xi[64 * 256];
  __shared__ __align__(16) bf16 Xj[128 * 128];
  __shared__ __align__(16) bf16 Pb[64 * 128];
  __shared__ __align__(16) bf16 Pw[64 * 128];
  __shared__ __align__(16) bf16 Vt[256 * 64];
  __shared__ unsigned lut[2048];

  const int tid = threadIdx.x;
  const int wave = tid >> 6, lane = tid & 63;
  const int quad = lane >> 4, r16 = lane & 15;
  const int par = lane & 1;
  const int wm = (wave >> 2) * 32;   // row tile (i) for S and PV
  const int wns = (wave & 3) * 32;   // S col tile (j)
  const int wnp = (wave & 3) * 64;   // PV col tile (d)
  const int i0 = blockIdx.x * 64;
  const int split = blockIdx.y;
  const int b = blockIdx.z;

  for (int i = tid; i < 2048; i += 512) {
    float t = (i + 0.5f) * (1.f / 2048.f);
    float bv = b3(4.f * t);
    float wv = b3(8.f * t) - b3(8.f * t - 4.f);
    lut[i] = (unsigned)f2bf(bv) | ((unsigned)f2bf(wv) << 16);
  }

  // stage Xi [64][256] once (x rows i0..i0+63 of this batch)
  {
    char* XiC = (char*)Xi;
    const bf16* src = U + (size_t)(b * 4096 + i0) * 1280;
#pragma unroll
    for (int q = 0; q < 4; ++q) {
      const int ch = tid + 512 * q;
      const int r = ch >> 5, c = (ch & 31) * 8;
      async16(src + (size_t)r * 1280 + c, XiC + q * 8192 + wave * 1024);
    }
  }

  const float* sqr = sqv + b * 4096;
  float sqi[8];
#pragma unroll
  for (int mi = 0; mi < 2; ++mi)
#pragma unroll
    for (int r = 0; r < 4; ++r)
      sqi[mi * 4 + r] = sqr[i0 + wm + mi * 16 + quad * 4 + r];

  v4f acc[2][2][4];  // [kern][mi][ni] PV accumulators
#pragma unroll
  for (int k2 = 0; k2 < 2; ++k2)
#pragma unroll
    for (int mi = 0; mi < 2; ++mi)
#pragma unroll
      for (int ni = 0; ni < 4; ++ni) acc[k2][mi][ni] = (v4f){0.f, 0.f, 0.f, 0.f};

  const bf16* Vb = VbB + (size_t)b * bmul * 256 * 4096;
  const bf16* Vw = VwB + (size_t)b * bmul * 256 * 4096;
  const float cexp = -1.4426950408889634f / 512.f;  // -log2(e)/512

  for (int jt = 0; jt < 8; ++jt) {
    const int j0g = split * 1024 + jt * 128;
    // ---- S phase: accs = Xi @ Xj^T, K=256 staged in two 128-col halves ----
    v4f accs[2][2];
#pragma unroll
    for (int mi = 0; mi < 2; ++mi)
#pragma unroll
      for (int ni = 0; ni < 2; ++ni) accs[mi][ni] = (v4f){0.f, 0.f, 0.f, 0.f};
    char* XjC = (char*)Xj;
    const bf16* bsrc = U + (size_t)(b * 4096 + j0g) * 1280;
#pragma unroll
    for (int kh = 0; kh < 2; ++kh) {
#pragma unroll
      for (int q = 0; q < 4; ++q) {
        const int ch = tid + 512 * q;
        const int r = ch >> 4, c = (ch & 15) * 8;
        async16(bsrc + (size_t)r * 1280 + kh * 128 + c,
                XjC + q * 8192 + wave * 1024);
      }
      __syncthreads();
#pragma unroll
      for (int ks = 0; ks < 4; ++ks) {
        v8s af[2], bfr[2];
#pragma unroll
        for (int mi = 0; mi < 2; ++mi)
          af[mi] = *(const v8s*)(Xi + (wm + mi * 16 + r16) * 256 + kh * 128 +
                                 ks * 32 + quad * 8);
#pragma unroll
        for (int ni = 0; ni < 2; ++ni)
          bfr[ni] = *(const v8s*)(Xj + (wns + ni * 16 + r16) * 128 + ks * 32 +
                                  quad * 8);
#pragma unroll
        for (int mi = 0; mi < 2; ++mi)
#pragma unroll
          for (int ni = 0; ni < 2; ++ni)
            accs[mi][ni] = __builtin_amdgcn_mfma_f32_16x16x32_bf16(
                af[mi], bfr[ni], accs[mi][ni], 0, 0, 0);
      }
      if (kh == 0) __syncthreads();  // protect Xj restage; kh==1 readers are
                                     // covered by the post-P-write barrier
    }
    // ---- spline epilogue: d2 -> LUT -> P_b,P_w into LDS (paired dwords) ----
    float sqj[2];
#pragma unroll
    for (int ni = 0; ni < 2; ++ni) sqj[ni] = sqr[j0g + wns + ni * 16 + r16];
#pragma unroll
    for (int mi = 0; mi < 2; ++mi) {
#pragma unroll
      for (int ni = 0; ni < 2; ++ni) {
        unsigned pv[4];
#pragma unroll
        for (int r = 0; r < 4; ++r) {
          float s = accs[mi][ni][r];
          float d2 = fmaxf(sqi[mi * 4 + r] + sqj[ni] - 2.f * s, 0.f);
          float t = __builtin_amdgcn_exp2f(d2 * cexp);
          int idx = (int)fminf(t * 2048.f, 2047.f);
          pv[r] = lut[idx];
        }
        unsigned ov[4];
#pragma unroll
        for (int r = 0; r < 4; ++r) ov[r] = __shfl_xor((int)pv[r], 1, 64);
#pragma unroll
        for (int rr = 0; rr < 2; ++rr) {
          const int r = par * 2 + rr;
          const unsigned ea = pv[r], eb = ov[r];
          const unsigned lo = par ? eb : ea;  // even column
          const unsigned hi = par ? ea : eb;  // odd column
          const int row = wm + mi * 16 + quad * 4 + r;
          const int colp = wns + ni * 16 + (r16 & ~1);
          *(unsigned*)(Pb + row * 128 + colp) = (lo & 0xffffu) | (hi << 16);
          *(unsigned*)(Pw + row * 128 + colp) =
              (lo >> 16) | (hi & 0xffff0000u);
        }
      }
    }
    __syncthreads();
    // ---- PV phase: acc[kern] += P_kern @ Vt, 4 stages (kern x j-half) ----
    char* VtC = (char*)Vt;
#pragma unroll
    for (int kv = 0; kv < 4; ++kv) {
      const int kern = kv >> 1, jh = kv & 1;
      const bf16* vsrc = (kern ? Vw : Vb) + j0g + jh * 64;
#pragma unroll
      for (int q = 0; q < 4; ++q) {
        const int ch = tid + 512 * q;
        const int r = ch >> 3, c = (ch & 7) * 8;
        async16(vsrc + (size_t)r * 4096 + c, VtC + q * 8192 + wave * 1024);
      }
      __syncthreads();
      const bf16* P = kern ? Pw : Pb;
#pragma unroll
      for (int ks = 0; ks < 2; ++ks) {
        v8s pa[2], bv[4];
#pragma unroll
        for (int mi = 0; mi < 2; ++mi)
          pa[mi] = *(const v8s*)(P + (wm + mi * 16 + r16) * 128 + jh * 64 +
                                 ks * 32 + quad * 8);
#pragma unroll
        for (int ni = 0; ni < 4; ++ni)
          bv[ni] = *(const v8s*)(Vt + (wnp + ni * 16 + r16) * 64 + ks * 32 +
                                 quad * 8);
#pragma unroll
        for (int mi = 0; mi < 2; ++mi)
#pragma unroll
          for (int ni = 0; ni < 4; ++ni)
            acc[kern][mi][ni] = __builtin_amdgcn_mfma_f32_16x16x32_bf16(
                pa[mi], bv[ni], acc[kern][mi][ni], 0, 0, 0);
      }
      __syncthreads();
    }
  }
  // ---- write bf16 partials (packed pairs, dword stores) ----
#pragma unroll
  for (int kern = 0; kern < 2; ++kern) {
    bf16* H = hpart + ((size_t)split * 4 + b * 2 + kern) * 4096 * 256;
#pragma unroll
    for (int mi = 0; mi < 2; ++mi) {
#pragma unroll
      for (int ni = 0; ni < 4; ++ni) {
        unsigned pv[4];
#pragma unroll
        for (int r = 0; r < 4; ++r)
          pv[r] = (unsigned)f2bf(acc[kern][mi][ni][r]);
        unsigned ov[4];
#pragma unroll
        for (int r = 0; r < 4; ++r) ov[r] = __shfl_xor((int)pv[r], 1, 64);
#pragma unroll
        for (int rr = 0; rr < 2; ++rr) {
          const int r = par * 2 + rr;
          const unsigned ea = pv[r], eb = ov[r];
          const unsigned lo = par ? eb : ea;
          const unsigned hi = par ? ea : eb;
          const int i = i0 + wm + mi * 16 + quad * 4 + r;
          const int colp = wnp + ni * 16 + (r16 & ~1);
          *(unsigned*)(H + (size_t)i * 256 + colp) = lo | (hi << 16);
        }
      }
    }
  }
}

// sum the four bf16 split-K partials; write bf16 slice into U[:, uoff..] and
// (pass 1 only) transposed bf16 into hT [z][256][4096].
__global__ void reduceT(const bf16* __restrict__ hpart, bf16* __restrict__ U,
                        bf16* __restrict__ hT, int uoffBase) {
  __shared__ float tile[64][65];
  const int z = blockIdx.z;
  const int b = z >> 1, kern = z & 1;
  const int uoff = uoffBase + kern * 512;
  const int n0 = blockIdx.x * 64, d0 = blockIdx.y * 64;
  const int tx = threadIdx.x & 31, ty = threadIdx.x >> 5;
  const size_t sstride = (size_t)4 * 4096 * 256;
  const bf16* s0 = hpart + (size_t)z * 4096 * 256;
#pragma unroll
  for (int i = 0; i < 8; ++i) {
    const int r = ty + i * 8;
    const size_t off = (size_t)(n0 + r) * 256 + d0 + tx * 2;
    float vx = 0.f, vy = 0.f;
#pragma unroll
    for (int k = 0; k < 4; ++k) {
      const unsigned dw = *(const unsigned*)(s0 + k * sstride + off);
      vx += bflo(dw);
      vy += bfhi(dw);
    }
    tile[r][tx * 2] = vx;
    tile[r][tx * 2 + 1] = vy;
    __hip_bfloat162 p;
    p.x = __float2bfloat16(vx);
    p.y = __float2bfloat16(vy);
    *(__hip_bfloat162*)(U + (size_t)(b * 4096 + n0 + r) * 1280 + uoff + d0 +
                        tx * 2) = p;
  }
  if (hT) {
    __syncthreads();
#pragma unroll
    for (int i = 0; i < 8; ++i) {
      const int c = ty + i * 8;
      __hip_bfloat162 p;
      p.x = __float2bfloat16(tile[tx * 2][c]);
      p.y = __float2bfloat16(tile[tx * 2 + 1][c]);
      *(__hip_bfloat162*)(hT + (size_t)z * 256 * 4096 + (size_t)(d0 + c) * 4096 +
                          n0 + tx * 2) = p;
    }
  }
}

// out = relu(U @ Wbig + b_lin), M=8192, K=1280, N=128
__global__ __launch_bounds__(256, 4) void gemm_proj(
    const bf16* __restrict__ U, const bf16* __restrict__ WbT,
    const float* __restrict__ blin, float* __restrict__ out) {
  __shared__ __align__(16) bf16 As[128 * 64];
  __shared__ __align__(16) bf16 Bs[64 * 64];
  const bf16* A = U + (size_t)blockIdx.x * 128 * 1280;
  const bf16* B = WbT + (size_t)blockIdx.y * 64 * 1280;
  v4f acc[4][2];
#pragma unroll
  for (int a = 0; a < 4; ++a)
#pragma unroll
    for (int b2 = 0; b2 < 2; ++b2) acc[a][b2] = (v4f){0.f, 0.f, 0.f, 0.f};
  mfma_loop<2, 64>(A, B, 1280, 1280, 1280, As, Bs, acc);
  const int tid = threadIdx.x, wave = tid >> 6, lane = tid & 63;
  const int quad = lane >> 4, r16 = lane & 15;
  const int wm = (wave >> 1) * 64, wn = (wave & 1) * 32;
  const int i0 = blockIdx.x * 128 + wm + quad * 4;
  const int j0 = blockIdx.y * 64 + wn + r16;
#pragma unroll
  for (int mi = 0; mi < 4; ++mi)
#pragma unroll
    for (int r = 0; r < 4; ++r) {
      const int i = i0 + mi * 16 + r;
#pragma unroll
      for (int ni = 0; ni < 2; ++ni) {
        const int j = j0 + ni * 16;
        out[(size_t)i * 128 + j] = fmaxf(acc[mi][ni][r] + blin[j], 0.f);
      }
    }
}

extern "C" void kernel_launch(void* const* d_in, const int* in_sizes, int n_in,
                              void* d_out, int out_size, void* d_ws,
                              size_t ws_size, hipStream_t stream) {
  const float* x = (const float*)d_in[0];
  const float* Wk = (const float*)d_in[1];
  const float* Wlin = (const float*)d_in[2];
  const float* blin = (const float*)d_in[3];
  float* out = (float*)d_out;
  char* w = (char*)d_ws;
  // workspace layout (bytes) — kmat eliminated (was 134 MB):
  bf16* hpart = (bf16*)(w);               // 4*4*4096*256*2    = 33554432
  bf16* h1T = (bf16*)(w + 33554432);      // 4 * 256*4096 * 2  = 8388608
  bf16* xhT = (bf16*)(w + 41943040);      // 2 * 256*4096 * 2  = 4194304
  bf16* U = (bf16*)(w + 46137344);        // 8192*1280 * 2     = 20971520
  bf16* WbT = (bf16*)(w + 67108864);      // 128*1280 * 2      = 327680
  float* sqv = (float*)(w + 67436544);    // 8192 * 4          = 32768
  // total ~67.5 MB

  prep<<<dim3(4096, 2), 256, 0, stream>>>(x, U, sqv);
  transk<<<dim3(64, 4, 2), 256, 0, stream>>>(x, xhT);
  wbig<<<dim3(640), 256, 0, stream>>>(Wk, Wlin, WbT);
  // pass 1: h1 = spline(x x^T) @ x   (V^T = xhT, shared by both kernels)
  fused_kh<<<dim3(64, 4, 2), 512, 0, stream>>>(U, sqv, xhT, xhT, 1, hpart);
  reduceT<<<dim3(64, 4, 4), 256, 0, stream>>>(hpart, U, h1T, 256);
  // pass 2: h2 = spline(x x^T) @ h1  (V^T per kernel chain from h1T)
  fused_kh<<<dim3(64, 4, 2), 512, 0, stream>>>(
      U, sqv, h1T, h1T + (size_t)256 * 4096, 2, hpart);
  reduceT<<<dim3(64, 4, 4), 256, 0, stream>>>(hpart, U, nullptr, 512);
  gemm_proj<<<dim3(64, 2), 256, 0, stream>>>(U, WbT, blin, out);
}

// Round 2
// 324.035 us; speedup vs baseline: 1.5441x; 1.5441x over previous
//
#include <hip/hip_runtime.h>
#include <hip/hip_bf16.h>

typedef __hip_bfloat16 bf16;
typedef float v4f __attribute__((ext_vector_type(4)));
typedef short v8s __attribute__((ext_vector_type(8)));

typedef const __attribute__((address_space(1))) void gvoid;
typedef __attribute__((address_space(3))) void lvoid;

__device__ __forceinline__ void async16(const void* g, void* l) {
  __builtin_amdgcn_global_load_lds((gvoid*)g, (lvoid*)l, 16, 0, 0);
}

__device__ __forceinline__ unsigned short f2bf(float v) {
  __hip_bfloat16 h = __float2bfloat16(v);
  return *(unsigned short*)&h;
}
__device__ __forceinline__ float bflo(unsigned dw) {
  unsigned u = dw << 16;
  return *(float*)&u;
}
__device__ __forceinline__ float bfhi(unsigned dw) {
  unsigned u = dw & 0xffff0000u;
  return *(float*)&u;
}

// cardinal cubic B-spline on [0,4], 0 outside. Reference bspline(t) == b3(4t),
// wavelet(t) == b3(8t) - b3(8t-4). Clamp makes u>=4 exactly 0 (64-108+48-4).
__device__ __forceinline__ float b3(float u) {
  u = fminf(fmaxf(u, 0.f), 4.f);
  float t1 = fmaxf(u - 1.f, 0.f);
  float t2 = fmaxf(u - 2.f, 0.f);
  float t3 = fmaxf(u - 3.f, 0.f);
  float c0 = u * u * u;
  float c1 = t1 * t1 * t1;
  float c2 = t2 * t2 * t2;
  float c3 = t3 * t3 * t3;
  return (c0 - 4.f * c1 + 6.f * c2 - 4.f * c3) * (1.f / 6.f);
}

// m97-style NT GEMM mainloop (used by gemm_proj): C[128 x NI*32] tile.
template <int NI, int BK>
__device__ __forceinline__ void mfma_loop(const bf16* __restrict__ A,
                                          const bf16* __restrict__ B, int lda,
                                          int ldb, int kLen, bf16* As, bf16* Bs,
                                          v4f acc[4][NI]) {
  const int tid = threadIdx.x;
  const int wave = tid >> 6;
  const int lane = tid & 63;
  const int quad = lane >> 4;
  const int r16 = lane & 15;
  const int wm = (wave >> 1) * 64;
  const int wn = (wave & 1) * (NI * 16);
  constexpr int CPR = BK / 8;          // 16B chunks per row
  constexpr int AQ = 128 * CPR / 256;  // async groups for A
  constexpr int BQ = NI * 32 * CPR / 256;
  char* AsC = (char*)As;
  char* BsC = (char*)Bs;
  for (int kk = 0; kk < kLen; kk += BK) {
#pragma unroll
    for (int q = 0; q < AQ; ++q) {
      const int ch = tid + 256 * q;
      const int r = ch / CPR, c = (ch % CPR) * 8;
      async16(A + (size_t)r * lda + kk + c, AsC + q * 4096 + wave * 1024);
    }
#pragma unroll
    for (int q = 0; q < BQ; ++q) {
      const int ch = tid + 256 * q;
      const int r = ch / CPR, c = (ch % CPR) * 8;
      async16(B + (size_t)r * ldb + kk + c, BsC + q * 4096 + wave * 1024);
    }
    __syncthreads();
#pragma unroll
    for (int ks = 0; ks < BK / 32; ++ks) {
      v8s af[4], bfr[NI];
#pragma unroll
      for (int mi = 0; mi < 4; ++mi)
        af[mi] =
            *(const v8s*)(As + (wm + mi * 16 + r16) * BK + ks * 32 + quad * 8);
#pragma unroll
      for (int ni = 0; ni < NI; ++ni)
        bfr[ni] =
            *(const v8s*)(Bs + (wn + ni * 16 + r16) * BK + ks * 32 + quad * 8);
#pragma unroll
      for (int mi = 0; mi < 4; ++mi)
#pragma unroll
        for (int ni = 0; ni < NI; ++ni)
          acc[mi][ni] = __builtin_amdgcn_mfma_f32_16x16x32_bf16(
              af[mi], bfr[ni], acc[mi][ni], 0, 0, 0);
    }
    __syncthreads();
  }
}

// per-row: sq-norm + bf16 cast of x into U[:, 0:256]
__global__ void prep(const float* __restrict__ x, bf16* __restrict__ U,
                     float* __restrict__ sq) {
  const int n = blockIdx.x, b = blockIdx.y, t = threadIdx.x;
  const size_t row = (size_t)b * 4096 + n;
  float v = x[row * 256 + t];
  U[row * 1280 + t] = __float2bfloat16(v);
  float s = v * v;
#pragma unroll
  for (int o = 32; o > 0; o >>= 1) s += __shfl_down(s, o, 64);
  __shared__ float ls[4];
  if ((t & 63) == 0) ls[t >> 6] = s;
  __syncthreads();
  if (t == 0) sq[row] = ls[0] + ls[1] + ls[2] + ls[3];
}

// fp32 [z][4096][256] -> bf16 [z][256][4096] (tiled transpose via LDS)
__global__ void transk(const float* __restrict__ src, bf16* __restrict__ dst) {
  __shared__ float tile[64][65];
  const int z = blockIdx.z;
  const float* s = src + (size_t)z * 4096 * 256;
  bf16* d = dst + (size_t)z * 256 * 4096;
  const int n0 = blockIdx.x * 64, d0 = blockIdx.y * 64;
  const int tx = threadIdx.x & 31, ty = threadIdx.x >> 5;
#pragma unroll
  for (int i = 0; i < 8; ++i) {
    const int r = ty + i * 8;
    const float2 v = *(const float2*)(s + (size_t)(n0 + r) * 256 + d0 + tx * 2);
    tile[r][tx * 2] = v.x;
    tile[r][tx * 2 + 1] = v.y;
  }
  __syncthreads();
#pragma unroll
  for (int i = 0; i < 8; ++i) {
    const int c = ty + i * 8;
    __hip_bfloat162 p;
    p.x = __float2bfloat16(tile[tx * 2][c]);
    p.y = __float2bfloat16(tile[tx * 2 + 1][c]);
    *(__hip_bfloat162*)(d + (size_t)(d0 + c) * 4096 + n0 + tx * 2) = p;
  }
}

// WbigT bf16 [128][1280]
__global__ void wbig(const float* __restrict__ Wk, const float* __restrict__ Wl,
                     bf16* __restrict__ WbT) {
  int idx = blockIdx.x * 256 + threadIdx.x;
  if (idx >= 128 * 1280) return;
  int j = idx / 1280, k = idx % 1280;
  int o = j & 63;
  float v = 0.f;
  if (k < 256)
    v = Wk[k * 64 + o] + Wl[k * 128 + j];
  else if (k < 512)
    v = (j < 64) ? Wk[16384 + (k - 256) * 64 + o] : 0.f;
  else if (k < 768)
    v = (j < 64) ? Wk[32768 + (k - 512) * 64 + o] : 0.f;
  else if (k < 1024)
    v = (j >= 64) ? Wk[16384 + (k - 768) * 64 + o] : 0.f;
  else
    v = (j >= 64) ? Wk[32768 + (k - 1024) * 64 + o] : 0.f;
  WbT[idx] = __float2bfloat16(v);
}

// Fused flash-style pass: h_partial[i, d] = sum_j spline(x_i . x_j) * V^T[d, j]
// for BOTH spline kernels. v2: all LDS buffers XOR-swizzled (was 16-way bank
// conflicted on every ds_read_b128: SQ_LDS_BANK_CONFLICT 6.2e7), and all
// stages ping-pong double-buffered with issue-before-compute so each
// vmcnt-drain barrier overlaps one compute phase (was serial stage->drain).
// Staged buffers swizzle via pre-swizzled GLOBAL source chunk (global_load_lds
// dest must stay linear); P buffers swizzle on VALU write + read.
// K-accumulation order, LUT, epilogue math identical to v1 (bit-exact).
// LDS: Xi 32K + Xj 2x16K + Pb/Pw 32K + Vt 2x16K + lut 8K = 136 KB.
__global__ __launch_bounds__(512, 2) void fused_kh(
    const bf16* __restrict__ U, const float* __restrict__ sqv,
    const bf16* __restrict__ VbB, const bf16* __restrict__ VwB, int bmul,
    bf16* __restrict__ hpart) {
  __shared__ __align__(16) bf16 Xi[64 * 256];     // swz8: rows 512B
  __shared__ __align__(16) bf16 Xj[2][128 * 64];  // swz8: rows 128B
  __shared__ __align__(16) bf16 Pb[64 * 128];     // swz8: rows 256B
  __shared__ __align__(16) bf16 Pw[64 * 128];     // swz8
  __shared__ __align__(16) bf16 Vt[2][256 * 32];  // swz4: rows 64B
  __shared__ unsigned lut[2048];

  const int tid = threadIdx.x;
  const int wave = tid >> 6, lane = tid & 63;
  const int quad = lane >> 4, r16 = lane & 15;
  const int par = lane & 1;
  const int wm = (wave >> 2) * 32;  // row tile (i) for S and PV
  const int wns = (wave & 3) * 32;  // S col tile (j)
  const int wnp = (wave & 3) * 64;  // PV col tile (d)
  const int i0 = blockIdx.x * 64;
  const int split = blockIdx.y;
  const int b = blockIdx.z;

  for (int i = tid; i < 2048; i += 512) {
    float t = (i + 0.5f) * (1.f / 2048.f);
    float bv = b3(4.f * t);
    float wv = b3(8.f * t) - b3(8.f * t - 4.f);
    lut[i] = (unsigned)f2bf(bv) | ((unsigned)f2bf(wv) << 16);
  }

  const bf16* Vb = VbB + (size_t)b * bmul * 256 * 4096;
  const bf16* Vw = VwB + (size_t)b * bmul * 256 * 4096;
  const bf16* Ub = U + (size_t)b * 4096 * 1280;

  // stage one K-quarter (64 cols) of Xj rows [j0g, j0g+128) into Xj[buf]
  auto stageXj = [&](int buf, int j0g, int kq) {
    char* C = (char*)Xj[buf];
    const bf16* src = Ub + (size_t)j0g * 1280 + kq * 64;
#pragma unroll
    for (int q = 0; q < 2; ++q) {
      const int ch = tid + 512 * q;
      const int r = ch >> 3, cp = ch & 7;
      async16(src + (size_t)r * 1280 + ((cp ^ (r & 7)) << 3),
              C + q * 8192 + wave * 1024);
    }
  };
  // stage Vt[buf] = V^T[kern][0:256][j0g + jc*32 ..+32)
  auto stageVt = [&](int buf, int s, int j0g) {
    const int kern = s >> 2, jc = s & 3;
    const bf16* src = (kern ? Vw : Vb) + j0g + jc * 32;
    char* C = (char*)Vt[buf];
#pragma unroll
    for (int q = 0; q < 2; ++q) {
      const int ch = tid + 512 * q;
      const int r = ch >> 2, cp = ch & 3;
      async16(src + (size_t)r * 4096 + ((cp ^ (r & 3)) << 3),
              C + q * 8192 + wave * 1024);
    }
  };

  // prologue: Xi (once) + first Xj quarter
  {
    char* XiC = (char*)Xi;
    const bf16* src = Ub + (size_t)i0 * 1280;
#pragma unroll
    for (int q = 0; q < 4; ++q) {
      const int ch = tid + 512 * q;
      const int r = ch >> 5, cp = ch & 31;
      async16(src + (size_t)r * 1280 + ((cp ^ (r & 7)) << 3),
              XiC + q * 8192 + wave * 1024);
    }
  }
  stageXj(0, split * 1024, 0);

  const float* sqr = sqv + b * 4096;
  float sqi[8];
#pragma unroll
  for (int mi = 0; mi < 2; ++mi)
#pragma unroll
    for (int r = 0; r < 4; ++r)
      sqi[mi * 4 + r] = sqr[i0 + wm + mi * 16 + quad * 4 + r];

  v4f acc[2][2][4];  // [kern][mi][ni] PV accumulators
#pragma unroll
  for (int k2 = 0; k2 < 2; ++k2)
#pragma unroll
    for (int mi = 0; mi < 2; ++mi)
#pragma unroll
      for (int ni = 0; ni < 4; ++ni) acc[k2][mi][ni] = (v4f){0.f, 0.f, 0.f, 0.f};

  const float cexp = -1.4426950408889634f / 512.f;  // -log2(e)/512
  __syncthreads();  // Xi + Xj[0] ready

  for (int jt = 0; jt < 8; ++jt) {
    const int j0g = split * 1024 + jt * 128;
    // early sq loads for the epilogue (latency hidden under S phase)
    float sqj[2];
#pragma unroll
    for (int ni = 0; ni < 2; ++ni) sqj[ni] = sqr[j0g + wns + ni * 16 + r16];

    // ---- S phase: accs = Xi @ Xj^T over 4 K-quarters, ping-pong ----
    v4f accs[2][2];
#pragma unroll
    for (int mi = 0; mi < 2; ++mi)
#pragma unroll
      for (int ni = 0; ni < 2; ++ni) accs[mi][ni] = (v4f){0.f, 0.f, 0.f, 0.f};
#pragma unroll
    for (int kq = 0; kq < 4; ++kq) {
      if (kq < 3)
        stageXj((kq + 1) & 1, j0g, kq + 1);
      else
        stageVt(0, 0, j0g);  // first PV stage prefetch
      const bf16* Xq = Xj[kq & 1];
      __builtin_amdgcn_s_setprio(1);
#pragma unroll
      for (int ks = 0; ks < 2; ++ks) {
        v8s af[2], bfr[2];
#pragma unroll
        for (int mi = 0; mi < 2; ++mi) {
          const int row = wm + mi * 16 + r16;
          const int ck = kq * 8 + ks * 4 + quad;
          af[mi] = *(const v8s*)(Xi + row * 256 + ((ck ^ (row & 7)) << 3));
        }
#pragma unroll
        for (int ni = 0; ni < 2; ++ni) {
          const int row = wns + ni * 16 + r16;
          const int ck = ks * 4 + quad;
          bfr[ni] = *(const v8s*)(Xq + row * 64 + ((ck ^ (row & 7)) << 3));
        }
#pragma unroll
        for (int mi = 0; mi < 2; ++mi)
#pragma unroll
          for (int ni = 0; ni < 2; ++ni)
            accs[mi][ni] = __builtin_amdgcn_mfma_f32_16x16x32_bf16(
                af[mi], bfr[ni], accs[mi][ni], 0, 0, 0);
      }
      __builtin_amdgcn_s_setprio(0);
      __syncthreads();
    }
    // ---- spline epilogue: d2 -> LUT -> P_b,P_w into LDS (swizzled) ----
#pragma unroll
    for (int mi = 0; mi < 2; ++mi) {
#pragma unroll
      for (int ni = 0; ni < 2; ++ni) {
        unsigned pv[4];
#pragma unroll
        for (int r = 0; r < 4; ++r) {
          float s = accs[mi][ni][r];
          float d2 = fmaxf(sqi[mi * 4 + r] + sqj[ni] - 2.f * s, 0.f);
          float t = __builtin_amdgcn_exp2f(d2 * cexp);
          int idx = (int)fminf(t * 2048.f, 2047.f);
          pv[r] = lut[idx];
        }
        unsigned ov[4];
#pragma unroll
        for (int r = 0; r < 4; ++r) ov[r] = __shfl_xor((int)pv[r], 1, 64);
#pragma unroll
        for (int rr = 0; rr < 2; ++rr) {
          const int r = par * 2 + rr;
          const unsigned ea = pv[r], eb = ov[r];
          const unsigned lo = par ? eb : ea;  // even column
          const unsigned hi = par ? ea : eb;  // odd column
          const int row = wm + mi * 16 + quad * 4 + r;
          const int colp = wns + ni * 16 + (r16 & ~1);
          const int eoff =
              row * 128 + (((colp >> 3) ^ (row & 7)) << 3) + (colp & 7);
          *(unsigned*)(Pb + eoff) = (lo & 0xffffu) | (hi << 16);
          *(unsigned*)(Pw + eoff) = (lo >> 16) | (hi & 0xffff0000u);
        }
      }
    }
    __syncthreads();  // P visible; Vt[0] ready (staged during kq=3)
    // ---- PV phase: 8 stages (kern x j-chunk32), ping-pong Vt ----
#pragma unroll
    for (int s = 0; s < 8; ++s) {
      if (s < 7)
        stageVt((s + 1) & 1, s + 1, j0g);
      else if (jt < 7)
        stageXj(0, j0g + 128, 0);  // next jt's first quarter
      const int kn = s >> 2, jc = s & 3;
      const bf16* P = kn ? Pw : Pb;
      const bf16* Vq = Vt[s & 1];
      __builtin_amdgcn_s_setprio(1);
      v8s pa[2], bv[4];
#pragma unroll
      for (int mi = 0; mi < 2; ++mi) {
        const int row = wm + mi * 16 + r16;
        const int ck = jc * 4 + quad;
        pa[mi] = *(const v8s*)(P + row * 128 + ((ck ^ (row & 7)) << 3));
      }
#pragma unroll
      for (int ni = 0; ni < 4; ++ni) {
        const int row = wnp + ni * 16 + r16;
        bv[ni] = *(const v8s*)(Vq + row * 32 + ((quad ^ (row & 3)) << 3));
      }
#pragma unroll
      for (int mi = 0; mi < 2; ++mi)
#pragma unroll
        for (int ni = 0; ni < 4; ++ni)
          acc[kn][mi][ni] = __builtin_amdgcn_mfma_f32_16x16x32_bf16(
              pa[mi], bv[ni], acc[kn][mi][ni], 0, 0, 0);
      __builtin_amdgcn_s_setprio(0);
      __syncthreads();
    }
  }
  // ---- write bf16 partials (packed pairs, dword stores) ----
#pragma unroll
  for (int kern = 0; kern < 2; ++kern) {
    bf16* H = hpart + ((size_t)split * 4 + b * 2 + kern) * 4096 * 256;
#pragma unroll
    for (int mi = 0; mi < 2; ++mi) {
#pragma unroll
      for (int ni = 0; ni < 4; ++ni) {
        unsigned pv[4];
#pragma unroll
        for (int r = 0; r < 4; ++r)
          pv[r] = (unsigned)f2bf(acc[kern][mi][ni][r]);
        unsigned ov[4];
#pragma unroll
        for (int r = 0; r < 4; ++r) ov[r] = __shfl_xor((int)pv[r], 1, 64);
#pragma unroll
        for (int rr = 0; rr < 2; ++rr) {
          const int r = par * 2 + rr;
          const unsigned ea = pv[r], eb = ov[r];
          const unsigned lo = par ? eb : ea;
          const unsigned hi = par ? ea : eb;
          const int i = i0 + wm + mi * 16 + quad * 4 + r;
          const int colp = wnp + ni * 16 + (r16 & ~1);
          *(unsigned*)(H + (size_t)i * 256 + colp) = lo | (hi << 16);
        }
      }
    }
  }
}

// sum the four bf16 split-K partials; write bf16 slice into U[:, uoff..] and
// (pass 1 only) transposed bf16 into hT [z][256][4096].
__global__ void reduceT(const bf16* __restrict__ hpart, bf16* __restrict__ U,
                        bf16* __restrict__ hT, int uoffBase) {
  __shared__ float tile[64][65];
  const int z = blockIdx.z;
  const int b = z >> 1, kern = z & 1;
  const int uoff = uoffBase + kern * 512;
  const int n0 = blockIdx.x * 64, d0 = blockIdx.y * 64;
  const int tx = threadIdx.x & 31, ty = threadIdx.x >> 5;
  const size_t sstride = (size_t)4 * 4096 * 256;
  const bf16* s0 = hpart + (size_t)z * 4096 * 256;
#pragma unroll
  for (int i = 0; i < 8; ++i) {
    const int r = ty + i * 8;
    const size_t off = (size_t)(n0 + r) * 256 + d0 + tx * 2;
    float vx = 0.f, vy = 0.f;
#pragma unroll
    for (int k = 0; k < 4; ++k) {
      const unsigned dw = *(const unsigned*)(s0 + k * sstride + off);
      vx += bflo(dw);
      vy += bfhi(dw);
    }
    tile[r][tx * 2] = vx;
    tile[r][tx * 2 + 1] = vy;
    __hip_bfloat162 p;
    p.x = __float2bfloat16(vx);
    p.y = __float2bfloat16(vy);
    *(__hip_bfloat162*)(U + (size_t)(b * 4096 + n0 + r) * 1280 + uoff + d0 +
                        tx * 2) = p;
  }
  if (hT) {
    __syncthreads();
#pragma unroll
    for (int i = 0; i < 8; ++i) {
      const int c = ty + i * 8;
      __hip_bfloat162 p;
      p.x = __float2bfloat16(tile[tx * 2][c]);
      p.y = __float2bfloat16(tile[tx * 2 + 1][c]);
      *(__hip_bfloat162*)(hT + (size_t)z * 256 * 4096 + (size_t)(d0 + c) * 4096 +
                          n0 + tx * 2) = p;
    }
  }
}

// out = relu(U @ Wbig + b_lin), M=8192, K=1280, N=128
__global__ __launch_bounds__(256, 4) void gemm_proj(
    const bf16* __restrict__ U, const bf16* __restrict__ WbT,
    const float* __restrict__ blin, float* __restrict__ out) {
  __shared__ __align__(16) bf16 As[128 * 64];
  __shared__ __align__(16) bf16 Bs[64 * 64];
  const bf16* A = U + (size_t)blockIdx.x * 128 * 1280;
  const bf16* B = WbT + (size_t)blockIdx.y * 64 * 1280;
  v4f acc[4][2];
#pragma unroll
  for (int a = 0; a < 4; ++a)
#pragma unroll
    for (int b2 = 0; b2 < 2; ++b2) acc[a][b2] = (v4f){0.f, 0.f, 0.f, 0.f};
  mfma_loop<2, 64>(A, B, 1280, 1280, 1280, As, Bs, acc);
  const int tid = threadIdx.x, wave = tid >> 6, lane = tid & 63;
  const int quad = lane >> 4, r16 = lane & 15;
  const int wm = (wave >> 1) * 64, wn = (wave & 1) * 32;
  const int i0 = blockIdx.x * 128 + wm + quad * 4;
  const int j0 = blockIdx.y * 64 + wn + r16;
#pragma unroll
  for (int mi = 0; mi < 4; ++mi)
#pragma unroll
    for (int r = 0; r < 4; ++r) {
      const int i = i0 + mi * 16 + r;
#pragma unroll
      for (int ni = 0; ni < 2; ++ni) {
        const int j = j0 + ni * 16;
        out[(size_t)i * 128 + j] = fmaxf(acc[mi][ni][r] + blin[j], 0.f);
      }
    }
}

extern "C" void kernel_launch(void* const* d_in, const int* in_sizes, int n_in,
                              void* d_out, int out_size, void* d_ws,
                              size_t ws_size, hipStream_t stream) {
  const float* x = (const float*)d_in[0];
  const float* Wk = (const float*)d_in[1];
  const float* Wlin = (const float*)d_in[2];
  const float* blin = (const float*)d_in[3];
  float* out = (float*)d_out;
  char* w = (char*)d_ws;
  // workspace layout (bytes):
  bf16* hpart = (bf16*)(w);               // 4*4*4096*256*2    = 33554432
  bf16* h1T = (bf16*)(w + 33554432);      // 4 * 256*4096 * 2  = 8388608
  bf16* xhT = (bf16*)(w + 41943040);      // 2 * 256*4096 * 2  = 4194304
  bf16* U = (bf16*)(w + 46137344);        // 8192*1280 * 2     = 20971520
  bf16* WbT = (bf16*)(w + 67108864);      // 128*1280 * 2      = 327680
  float* sqv = (float*)(w + 67436544);    // 8192 * 4          = 32768
  // total ~67.5 MB

  prep<<<dim3(4096, 2), 256, 0, stream>>>(x, U, sqv);
  transk<<<dim3(64, 4, 2), 256, 0, stream>>>(x, xhT);
  wbig<<<dim3(640), 256, 0, stream>>>(Wk, Wlin, WbT);
  // pass 1: h1 = spline(x x^T) @ x   (V^T = xhT, shared by both kernels)
  fused_kh<<<dim3(64, 4, 2), 512, 0, stream>>>(U, sqv, xhT, xhT, 1, hpart);
  reduceT<<<dim3(64, 4, 4), 256, 0, stream>>>(hpart, U, h1T, 256);
  // pass 2: h2 = spline(x x^T) @ h1  (V^T per kernel chain from h1T)
  fused_kh<<<dim3(64, 4, 2), 512, 0, stream>>>(
      U, sqv, h1T, h1T + (size_t)256 * 4096, 2, hpart);
  reduceT<<<dim3(64, 4, 4), 256, 0, stream>>>(hpart, U, nullptr, 512);
  gemm_proj<<<dim3(64, 2), 256, 0, stream>>>(U, WbT, blin, out);
}